// Round 1
// baseline (1946.163 us; speedup 1.0000x reference)
//
#include <hip/hip_runtime.h>
#include <hip/hip_bf16.h>
#include <math.h>

// Problem constants
#define BB     256
#define NMEL   80
#define TMEL   800
#define NFR    16          // frames per step
#define TT     50          // decoder steps
#define RNN    1024
#define ENC    256
#define INDIM  1280        // RNN + ENC == MEL_DIM
#define G4     4096        // 4*RNN
#define MROWS  (TT*BB)     // 12800

typedef __attribute__((ext_vector_type(8))) short bf16x8;
typedef __attribute__((ext_vector_type(4))) float f32x4;

__device__ __forceinline__ unsigned short f2bf(float f) {
    unsigned int u = __float_as_uint(f);
    u += 0x7FFFu + ((u >> 16) & 1u);     // round-to-nearest-even
    return (unsigned short)(u >> 16);
}
__device__ __forceinline__ float bf2f(unsigned short s) {
    return __uint_as_float(((unsigned int)s) << 16);
}

// ---------------- prep kernels ----------------

__global__ void k_f32_to_bf16(const float* __restrict__ src,
                              unsigned short* __restrict__ dst, int n) {
    for (int i = blockIdx.x * blockDim.x + threadIdx.x; i < n;
         i += gridDim.x * blockDim.x)
        dst[i] = f2bf(src[i]);
}

// W_proj[:, 0:1024] -> bf16 [1280][1024]
__global__ void k_conv_wph(const float* __restrict__ wproj,
                           unsigned short* __restrict__ dst) {
    const int n = INDIM * RNN;
    for (int i = blockIdx.x * blockDim.x + threadIdx.x; i < n;
         i += gridDim.x * blockDim.x) {
        int m = i >> 10, k = i & 1023;
        dst[i] = f2bf(wproj[m * INDIM + k]);
    }
}

// teacher-forced inputs: frames[t][b][k] = (t==0)?0:target[b][k%80][t*16+k/80]
__global__ void k_frames(const float* __restrict__ target,
                         unsigned short* __restrict__ frames) {
    const int n = TT * BB * INDIM;
    for (int i = blockIdx.x * blockDim.x + threadIdx.x; i < n;
         i += gridDim.x * blockDim.x) {
        int k = i % INDIM;
        int rb = i / INDIM;
        int b = rb & (BB - 1);
        int t = rb >> 8;
        unsigned short v = 0;
        if (t > 0) {
            int mel = k % NMEL, fr = k / NMEL;
            v = f2bf(target[(b * NMEL + mel) * TMEL + t * NFR + fr]);
        }
        frames[i] = v;
    }
}

// ctxproj[b][m] = b_proj[m] + context[b]·W_proj[m][1024:1280]
__global__ void k_ctxproj(const float* __restrict__ context,
                          const float* __restrict__ wproj,
                          const float* __restrict__ bproj,
                          float* __restrict__ ctx) {
    int i = blockIdx.x * blockDim.x + threadIdx.x;
    if (i >= BB * INDIM) return;
    int m = i % INDIM, b = i / INDIM;
    const float* wr = wproj + m * INDIM + RNN;
    const float* cb = context + b * ENC;
    float acc = bproj[m];
    for (int e = 0; e < ENC; ++e) acc += cb[e] * wr[e];
    ctx[i] = acc;
}

// gatectx[b] = b_gate + context[b]·W_gate[0][1024:1280]
__global__ void k_gatectx(const float* __restrict__ context,
                          const float* __restrict__ wgate,
                          const float* __restrict__ bgate,
                          float* __restrict__ gctx) {
    int b = blockIdx.x * blockDim.x + threadIdx.x;
    if (b >= BB) return;
    float acc = bgate[0];
    const float* cb = context + b * ENC;
    for (int e = 0; e < ENC; ++e) acc += cb[e] * wgate[RNN + e];
    gctx[b] = acc;
}

// ---------------- GEMM 1: xproj = frames @ W_ih^T + b_ih + b_hh (bf16 out) ----
// M=12800 N=4096 K=1280. 128x128 WG tile, 4 waves of 64x64, direct-global frags.
__global__ __launch_bounds__(256) void k_gemm_xproj(
    const unsigned short* __restrict__ A,   // [12800][1280]
    const unsigned short* __restrict__ Bw,  // [4096][1280]
    const float* __restrict__ b_ih, const float* __restrict__ b_hh,
    unsigned short* __restrict__ Cout)      // [12800][4096]
{
    const int lane = threadIdx.x & 63, wid = threadIdx.x >> 6;
    const int mw = blockIdx.y * 128 + (wid >> 1) * 64;
    const int nw = blockIdx.x * 128 + (wid & 1) * 64;
    const int lr = lane & 15, lk = (lane >> 4) * 8;
    f32x4 acc[4][4] = {};
    const unsigned short* Ab = A + (mw + lr) * INDIM + lk;
    const unsigned short* Bb = Bw + (nw + lr) * INDIM + lk;
    #pragma unroll 2
    for (int k = 0; k < INDIM; k += 32) {
        bf16x8 af[4], bfv[4];
        #pragma unroll
        for (int mi = 0; mi < 4; ++mi)
            af[mi] = *(const bf16x8*)(Ab + mi * 16 * INDIM + k);
        #pragma unroll
        for (int ni = 0; ni < 4; ++ni)
            bfv[ni] = *(const bf16x8*)(Bb + ni * 16 * INDIM + k);
        #pragma unroll
        for (int mi = 0; mi < 4; ++mi)
            #pragma unroll
            for (int ni = 0; ni < 4; ++ni)
                acc[mi][ni] = __builtin_amdgcn_mfma_f32_16x16x32_bf16(
                    af[mi], bfv[ni], acc[mi][ni], 0, 0, 0);
    }
    #pragma unroll
    for (int ni = 0; ni < 4; ++ni) {
        const int col = nw + ni * 16 + lr;
        const float bias = b_ih[col] + b_hh[col];
        #pragma unroll
        for (int mi = 0; mi < 4; ++mi) {
            const int row = mw + mi * 16 + (lane >> 4) * 4;
            #pragma unroll
            for (int r = 0; r < 4; ++r)
                Cout[(row + r) * G4 + col] = f2bf(acc[mi][ni][r] + bias);
        }
    }
}

// ---------------- per-step fused kernel ----------------
// gates = xproj[t] + h_prev @ W_hh^T ; LSTM cell ; write h_next(bf16), c(f32)
// Block = 4 waves; wave g computes gate g's 32x32 tile. Grid (1024/32, 256/32).
__global__ __launch_bounds__(256) void k_step(
    const unsigned short* __restrict__ Whh,     // [4096][1024]
    const unsigned short* __restrict__ xproj_t, // [256][4096]
    const unsigned short* __restrict__ h_prev,  // [256][1024]
    unsigned short* __restrict__ h_next,        // [256][1024]
    float* __restrict__ c)                      // [256][1024]
{
    __shared__ float lds[4][32][33];            // +1 pad: conflict-free
    const int lane = threadIdx.x & 63, g = threadIdx.x >> 6;
    const int m0 = blockIdx.y * 32, n0 = blockIdx.x * 32;
    const int lr = lane & 15, lk = (lane >> 4) * 8;
    f32x4 acc[2][2] = {};
    const unsigned short* Ab = h_prev + (m0 + lr) * RNN + lk;
    const unsigned short* Bb = Whh + (g * RNN + n0 + lr) * RNN + lk;
    #pragma unroll 8
    for (int k = 0; k < RNN; k += 32) {
        bf16x8 af[2], bfv[2];
        #pragma unroll
        for (int mi = 0; mi < 2; ++mi)
            af[mi] = *(const bf16x8*)(Ab + mi * 16 * RNN + k);
        #pragma unroll
        for (int ni = 0; ni < 2; ++ni)
            bfv[ni] = *(const bf16x8*)(Bb + ni * 16 * RNN + k);
        #pragma unroll
        for (int mi = 0; mi < 2; ++mi)
            #pragma unroll
            for (int ni = 0; ni < 2; ++ni)
                acc[mi][ni] = __builtin_amdgcn_mfma_f32_16x16x32_bf16(
                    af[mi], bfv[ni], acc[mi][ni], 0, 0, 0);
    }
    // add xproj contribution, park in LDS for cross-wave gate combine
    #pragma unroll
    for (int ni = 0; ni < 2; ++ni) {
        const int cl = ni * 16 + lr;
        #pragma unroll
        for (int mi = 0; mi < 2; ++mi) {
            const int rowl = mi * 16 + (lane >> 4) * 4;
            #pragma unroll
            for (int r = 0; r < 4; ++r)
                lds[g][rowl + r][cl] = acc[mi][ni][r] +
                    bf2f(xproj_t[(m0 + rowl + r) * G4 + g * RNN + n0 + cl]);
        }
    }
    __syncthreads();
    #pragma unroll
    for (int q = 0; q < 4; ++q) {
        const int e = threadIdx.x + q * 256;
        const int lm = e >> 5, ln = e & 31;
        const int b = m0 + lm, j = n0 + ln;
        const float xi = lds[0][lm][ln], xf = lds[1][lm][ln];
        const float xg = lds[2][lm][ln], xo = lds[3][lm][ln];
        const float si = 1.f / (1.f + expf(-xi));
        const float sf = 1.f / (1.f + expf(-xf));
        const float so = 1.f / (1.f + expf(-xo));
        const float cp = c[b * RNN + j];
        const float cn = sf * cp + si * tanhf(xg);
        const float hn = so * tanhf(cn);
        c[b * RNN + j] = cn;
        h_next[b * RNN + j] = f2bf(hn);
    }
}

// ---------------- GEMM 2: mel = h_all @ Wp_h^T + ctxproj, scatter to output ---
// M=12800 N=1280 K=1024
__global__ __launch_bounds__(256) void k_gemm_mel(
    const unsigned short* __restrict__ A,   // h_all+BB*RNN, [12800][1024]
    const unsigned short* __restrict__ Bw,  // Wp_h [1280][1024]
    const float* __restrict__ ctxproj,      // [256][1280]
    float* __restrict__ out0)               // [256][80][800]
{
    const int lane = threadIdx.x & 63, wid = threadIdx.x >> 6;
    const int mw = blockIdx.y * 128 + (wid >> 1) * 64;
    const int nw = blockIdx.x * 128 + (wid & 1) * 64;
    const int lr = lane & 15, lk = (lane >> 4) * 8;
    f32x4 acc[4][4] = {};
    const unsigned short* Ab = A + (mw + lr) * RNN + lk;
    const unsigned short* Bb = Bw + (nw + lr) * RNN + lk;
    #pragma unroll 2
    for (int k = 0; k < RNN; k += 32) {
        bf16x8 af[4], bfv[4];
        #pragma unroll
        for (int mi = 0; mi < 4; ++mi)
            af[mi] = *(const bf16x8*)(Ab + mi * 16 * RNN + k);
        #pragma unroll
        for (int ni = 0; ni < 4; ++ni)
            bfv[ni] = *(const bf16x8*)(Bb + ni * 16 * RNN + k);
        #pragma unroll
        for (int mi = 0; mi < 4; ++mi)
            #pragma unroll
            for (int ni = 0; ni < 4; ++ni)
                acc[mi][ni] = __builtin_amdgcn_mfma_f32_16x16x32_bf16(
                    af[mi], bfv[ni], acc[mi][ni], 0, 0, 0);
    }
    #pragma unroll
    for (int ni = 0; ni < 4; ++ni) {
        const int col = nw + ni * 16 + lr;       // k in [0,1280)
        const int mel = col % NMEL, fr = col / NMEL;
        #pragma unroll
        for (int mi = 0; mi < 4; ++mi) {
            const int row0 = mw + mi * 16 + (lane >> 4) * 4;
            #pragma unroll
            for (int r = 0; r < 4; ++r) {
                const int row = row0 + r;        // t*256 + b
                const int t = row >> 8, b = row & 255;
                out0[(b * NMEL + mel) * TMEL + t * NFR + fr] =
                    acc[mi][ni][r] + ctxproj[b * INDIM + col];
            }
        }
    }
}

// gate[b*50+t] = gatectx[b] + h_all[t+1][b]·w_gate[0:1024] ; one wave per row
__global__ void k_gate(const unsigned short* __restrict__ h,  // [12800][1024]
                       const float* __restrict__ wgate,
                       const float* __restrict__ gctx,
                       float* __restrict__ out1) {
    const int gw = (blockIdx.x * blockDim.x + threadIdx.x) >> 6;
    const int lane = threadIdx.x & 63;
    if (gw >= MROWS) return;
    const unsigned short* hr = h + gw * RNN + lane * 16;
    const float* wr = wgate + lane * 16;
    float acc = 0.f;
    #pragma unroll
    for (int j = 0; j < 16; ++j) acc += bf2f(hr[j]) * wr[j];
    for (int off = 32; off; off >>= 1) acc += __shfl_down(acc, off);
    if (lane == 0) {
        const int t = gw >> 8, b = gw & 255;
        out1[b * TT + t] = acc + gctx[b];
    }
}

// ---------------- launch ----------------

#define ALIGN_OK(x) (x)  // all offsets are multiples of 256 by construction
static const size_t OFF_WIH   = 0;                               // 4096*1280*2
static const size_t OFF_WHH   = OFF_WIH   + (size_t)G4 * INDIM * 2;
static const size_t OFF_WPH   = OFF_WHH   + (size_t)G4 * RNN * 2;
static const size_t OFF_FRM   = OFF_WPH   + (size_t)INDIM * RNN * 2;
static const size_t OFF_XPROJ = OFF_FRM   + (size_t)MROWS * INDIM * 2;
static const size_t OFF_HALL  = OFF_XPROJ + (size_t)MROWS * G4 * 2;   // 51 slots
static const size_t OFF_C     = OFF_HALL  + (size_t)(TT + 1) * BB * RNN * 2;
static const size_t OFF_CTX   = OFF_C     + (size_t)BB * RNN * 4;
static const size_t OFF_GCTX  = OFF_CTX   + (size_t)BB * INDIM * 4;

extern "C" void kernel_launch(void* const* d_in, const int* in_sizes, int n_in,
                              void* d_out, int out_size, void* d_ws, size_t ws_size,
                              hipStream_t stream) {
    const float* context = (const float*)d_in[0];
    const float* target  = (const float*)d_in[1];
    const float* W_ih    = (const float*)d_in[2];
    const float* b_ih    = (const float*)d_in[3];
    const float* W_hh    = (const float*)d_in[4];
    const float* b_hh    = (const float*)d_in[5];
    const float* W_proj  = (const float*)d_in[6];
    const float* b_proj  = (const float*)d_in[7];
    const float* W_gate  = (const float*)d_in[8];
    const float* b_gate  = (const float*)d_in[9];
    float* out = (float*)d_out;
    char* ws = (char*)d_ws;

    unsigned short* wih_bf  = (unsigned short*)(ws + OFF_WIH);
    unsigned short* whh_bf  = (unsigned short*)(ws + OFF_WHH);
    unsigned short* wph_bf  = (unsigned short*)(ws + OFF_WPH);
    unsigned short* frames  = (unsigned short*)(ws + OFF_FRM);
    unsigned short* xproj   = (unsigned short*)(ws + OFF_XPROJ);
    unsigned short* h_all   = (unsigned short*)(ws + OFF_HALL);
    float*          c_buf   = (float*)(ws + OFF_C);
    float*          ctxproj = (float*)(ws + OFF_CTX);
    float*          gctx    = (float*)(ws + OFF_GCTX);

    // init recurrent state (every call: harness does not re-zero ws)
    hipMemsetAsync(h_all, 0, (size_t)BB * RNN * 2, stream);   // h0 slot
    hipMemsetAsync(c_buf, 0, (size_t)BB * RNN * 4, stream);   // c0

    k_f32_to_bf16<<<2048, 256, 0, stream>>>(W_ih, wih_bf, G4 * INDIM);
    k_f32_to_bf16<<<2048, 256, 0, stream>>>(W_hh, whh_bf, G4 * RNN);
    k_conv_wph<<<2048, 256, 0, stream>>>(W_proj, wph_bf);
    k_frames<<<2048, 256, 0, stream>>>(target, frames);
    k_ctxproj<<<(BB * INDIM + 255) / 256, 256, 0, stream>>>(context, W_proj,
                                                            b_proj, ctxproj);
    k_gatectx<<<1, 256, 0, stream>>>(context, W_gate, b_gate, gctx);

    k_gemm_xproj<<<dim3(G4 / 128, MROWS / 128), 256, 0, stream>>>(
        frames, wih_bf, b_ih, b_hh, xproj);

    for (int t = 0; t < TT; ++t) {
        k_step<<<dim3(RNN / 32, BB / 32), 256, 0, stream>>>(
            whh_bf, xproj + (size_t)t * BB * G4,
            h_all + (size_t)t * BB * RNN,
            h_all + (size_t)(t + 1) * BB * RNN, c_buf);
    }

    k_gemm_mel<<<dim3(INDIM / 128, MROWS / 128), 256, 0, stream>>>(
        h_all + (size_t)BB * RNN, wph_bf, ctxproj, out);
    k_gate<<<MROWS / 4, 256, 0, stream>>>(h_all + (size_t)BB * RNN, W_gate,
                                          gctx, out + (size_t)BB * NMEL * TMEL);
}